// Round 10
// baseline (453.751 us; speedup 1.0000x reference)
//
#include <hip/hip_runtime.h>
#include <hip/hip_bf16.h>
#include <stdint.h>

#define DIM   1024
#define NSEQ  4096
#define NBAT  4
#define NH    16
#define HD    64
#define MROWS (NBAT*NSEQ)   // 16384

typedef __attribute__((ext_vector_type(8))) short  short8;
typedef __attribute__((ext_vector_type(4))) float  f32x4;
typedef __attribute__((ext_vector_type(4))) unsigned int  u32x4;
typedef __attribute__((ext_vector_type(8))) unsigned short u16x8;

// ---- helpers -------------------------------------------------------------
__device__ inline unsigned short bf16_rne(float x) {
    unsigned u = __builtin_bit_cast(unsigned, x);
    u += 0x7FFFu + ((u >> 16) & 1u);
    return (unsigned short)(u >> 16);
}
__device__ inline float bf16_to_f32(unsigned short h) {
    return __builtin_bit_cast(float, ((unsigned)h) << 16);
}
__device__ inline u16x8 cvt8(f32x4 a, f32x4 b) {
    u16x8 o;
    o[0] = bf16_rne(a[0]); o[1] = bf16_rne(a[1]); o[2] = bf16_rne(a[2]); o[3] = bf16_rne(a[3]);
    o[4] = bf16_rne(b[0]); o[5] = bf16_rne(b[1]); o[6] = bf16_rne(b[2]); o[7] = bf16_rne(b[3]);
    return o;
}
__device__ inline void gld16(const unsigned short* g, unsigned short* l) {
    __builtin_amdgcn_global_load_lds(
        (const __attribute__((address_space(1))) unsigned int*)g,
        (__attribute__((address_space(3))) unsigned int*)l,
        16, 0, 0);
}

// ---- all 4 weights fp32->bf16, one launch --------------------------------
__global__ __launch_bounds__(256) void wcvt_kernel(const float* __restrict__ s0, const float* __restrict__ s1,
                                                   const float* __restrict__ s2, const float* __restrict__ s3,
                                                   unsigned short* __restrict__ d0, unsigned short* __restrict__ d1,
                                                   unsigned short* __restrict__ d2, unsigned short* __restrict__ d3) {
    int i = blockIdx.x * 256 + threadIdx.x;     // 0..524287, 8 f32 each
    int w = i >> 17, j = i & 131071;
    const float* s = (w == 0) ? s0 : (w == 1) ? s1 : (w == 2) ? s2 : s3;
    unsigned short* d = (w == 0) ? d0 : (w == 1) ? d1 : (w == 2) ? d2 : d3;
    f32x4 a = ((const f32x4*)s)[2 * j];
    f32x4 b = ((const f32x4*)s)[2 * j + 1];
    ((u16x8*)d)[j] = cvt8(a, b);
}

// ==== shared GEMM geometry (256x256 tile, 8 waves, BK=32, ring-4 LDS) =====
// LDS swizzle + involution + bank math: verified r6 (436 µs e2e, absmax 4.9e-4).
#define SB0 __builtin_amdgcn_sched_barrier(0)
#define MF(i, j, A, B) acc[i][j] = __builtin_amdgcn_mfma_f32_16x16x32_bf16(A, B, acc[i][j], 0, 0, 0)

// ---- fused-convert GEMM: C_bf16 = act(A_fp32 @ W_bf16^T + bias) ----------
// A: fp32 global -> regs (2-tile-deep) -> cvt_pk bf16 -> ds_write (same LDS
// image gld16 produced). B: gld16 ring-3 unchanged. Per-iter VMEM: A x4 then
// B x2; queue=14 at pack point; vmcnt(8) retires exactly {A(kt+1)x4,B(kt+1)x2}.
template<int ACT>
__global__ __launch_bounds__(512, 2) void gemm8a32_kernel(const float* __restrict__ Af,
                                                          const unsigned short* __restrict__ Wb,
                                                          const float* __restrict__ bias,
                                                          unsigned short* __restrict__ Cp,
                                                          const int* __restrict__ mask) {
    __shared__ __align__(16) char smem[131072];   // A slots [0,64K), B slots [64K,128K)

    const int bid = blockIdx.x;
    const int swz = (bid & 7) * 32 + (bid >> 3);
    const int tm  = (swz >> 2) * 256;
    const int tn  = (swz & 3) * 256;

    const int t    = threadIdx.x;
    const int w    = t >> 6;
    const int lane = t & 63;
    const int wm   = w >> 2;
    const int wn   = w & 3;
    const int lm   = lane & 15;
    const int quad = lane >> 4;

    const int xr    = ((quad ^ ((lm >> 1) & 3)) << 4) + (lm & 1) * 64;
    const int abase = (wm * 64 + (lm >> 1)) * 128 + xr;
    const int bbase = (wn * 32 + (lm >> 1)) * 128 + xr;

    const int srow = ((t >> 3) << 1) + ((t >> 2) & 1);
    const int scol = ((t & 3) ^ ((t >> 3) & 3)) * 8;
    const float*          pa = Af + (size_t)(tm + srow) * DIM + scol;
    const unsigned short* pb = Wb + (size_t)(tn + srow) * DIM + scol;

    f32x4 acc[8][4] = {};
    const int NT = DIM / 32;

#define ALOAD(k, r0, r1, r2, r3) do {                          \
    r0 = *(const f32x4*)(pa + (k) * 32);                       \
    r1 = *(const f32x4*)(pa + (k) * 32 + 4);                   \
    r2 = *(const f32x4*)(pa + (k) * 32 + 128 * DIM);           \
    r3 = *(const f32x4*)(pa + (k) * 32 + 128 * DIM + 4); } while (0)
#define BSTAGE(k, sl) do {                                                    \
    char* dstb = smem + 65536 + (sl) * 16384;                                 \
    gld16(pb + (k) * 32,             (unsigned short*)(dstb + t * 16));       \
    gld16(pb + (k) * 32 + 128 * DIM, (unsigned short*)(dstb + 8192 + t * 16)); } while (0)
#define APACK(sl, r0, r1, r2, r3) do {                                           \
    unsigned w0, w1, w2, w3, w4, w5, w6, w7;                                     \
    asm("v_cvt_pk_bf16_f32 %0, %1, %2" : "=v"(w0) : "v"(r0[0]), "v"(r0[1]));     \
    asm("v_cvt_pk_bf16_f32 %0, %1, %2" : "=v"(w1) : "v"(r0[2]), "v"(r0[3]));     \
    asm("v_cvt_pk_bf16_f32 %0, %1, %2" : "=v"(w2) : "v"(r1[0]), "v"(r1[1]));     \
    asm("v_cvt_pk_bf16_f32 %0, %1, %2" : "=v"(w3) : "v"(r1[2]), "v"(r1[3]));     \
    asm("v_cvt_pk_bf16_f32 %0, %1, %2" : "=v"(w4) : "v"(r2[0]), "v"(r2[1]));     \
    asm("v_cvt_pk_bf16_f32 %0, %1, %2" : "=v"(w5) : "v"(r2[2]), "v"(r2[3]));     \
    asm("v_cvt_pk_bf16_f32 %0, %1, %2" : "=v"(w6) : "v"(r3[0]), "v"(r3[1]));     \
    asm("v_cvt_pk_bf16_f32 %0, %1, %2" : "=v"(w7) : "v"(r3[2]), "v"(r3[3]));     \
    char* sa = smem + (sl) * 16384;                                              \
    u32x4 d0v = {w0, w1, w2, w3}, d1v = {w4, w5, w6, w7};                        \
    *(u32x4*)(sa + t * 16) = d0v;                                                \
    *(u32x4*)(sa + 8192 + t * 16) = d1v; } while (0)

    // one full K-iteration: R* = regs holding A(kt+1) (packed this iter),
    // N* = regs receiving A(min(kt+2,NT-1)) (packed next iter).
#define ITER(kt, R0, R1, R2, R3, N0, N1, N2, N3) do {                            \
    const int ksa  = ((kt) + 2 < NT) ? (kt) + 2 : NT - 1;                        \
    const int ksb  = ((kt) + 3 < NT) ? (kt) + 3 : NT - 1;                        \
    const int slot = ((kt) & 3) * 16384;                                         \
    ALOAD(ksa, N0, N1, N2, N3); SB0;                                             \
    BSTAGE(ksb, ((kt) + 3) & 3); SB0;                                            \
    short8 af0 = *(const short8*)(smem + slot + abase);                          \
    short8 af1 = *(const short8*)(smem + slot + abase + 1024);                   \
    short8 af2 = *(const short8*)(smem + slot + abase + 2048);                   \
    short8 af3 = *(const short8*)(smem + slot + abase + 3072);                   \
    short8 bf0 = *(const short8*)(smem + slot + 65536 + bbase);                  \
    short8 bf1 = *(const short8*)(smem + slot + 65536 + bbase + 1024);           \
    short8 bf2 = *(const short8*)(smem + slot + 65536 + bbase + 2048);           \
    short8 bf3 = *(const short8*)(smem + slot + 65536 + bbase + 3072);           \
    __builtin_amdgcn_s_barrier();                                                \
    asm volatile("s_waitcnt lgkmcnt(0)" ::: "memory");                           \
    SB0;                                                                         \
    __builtin_amdgcn_s_setprio(1);                                               \
    MF(0,0,af0,bf0); MF(0,1,af0,bf1); MF(0,2,af0,bf2); MF(0,3,af0,bf3);          \
    MF(1,0,af1,bf0); MF(1,1,af1,bf1); MF(1,2,af1,bf2); MF(1,3,af1,bf3);          \
    MF(2,0,af2,bf0); MF(2,1,af2,bf1); MF(2,2,af2,bf2); MF(2,3,af2,bf3);          \
    MF(3,0,af3,bf0); MF(3,1,af3,bf1); MF(3,2,af3,bf2); MF(3,3,af3,bf3);          \
    __builtin_amdgcn_s_setprio(0);                                               \
    __builtin_amdgcn_s_barrier(); SB0;                                           \
    asm volatile("s_waitcnt vmcnt(8)" ::: "memory"); SB0;                        \
    APACK(((kt) + 1) & 3, R0, R1, R2, R3);                                       \
    short8 ag0 = *(const short8*)(smem + slot + abase + 4096);                   \
    short8 ag1 = *(const short8*)(smem + slot + abase + 4096 + 1024);            \
    short8 ag2 = *(const short8*)(smem + slot + abase + 4096 + 2048);            \
    short8 ag3 = *(const short8*)(smem + slot + abase + 4096 + 3072);            \
    __builtin_amdgcn_s_barrier();                                                \
    asm volatile("s_waitcnt lgkmcnt(0)" ::: "memory");                           \
    SB0;                                                                         \
    __builtin_amdgcn_s_setprio(1);                                               \
    MF(4,0,ag0,bf0); MF(4,1,ag0,bf1); MF(4,2,ag0,bf2); MF(4,3,ag0,bf3);          \
    MF(5,0,ag1,bf0); MF(5,1,ag1,bf1); MF(5,2,ag1,bf2); MF(5,3,ag1,bf3);          \
    MF(6,0,ag2,bf0); MF(6,1,ag2,bf1); MF(6,2,ag2,bf2); MF(6,3,ag2,bf3);          \
    MF(7,0,ag3,bf0); MF(7,1,ag3,bf1); MF(7,2,ag3,bf2); MF(7,3,ag3,bf3);          \
    __builtin_amdgcn_s_setprio(0);                                               \
    __builtin_amdgcn_s_barrier(); SB0; } while (0)

    f32x4 c0, c1, c2, c3, n0, n1, n2, n3;
    // prologue issue order: A0 x4, B0 x2, A1 x4, B1 x2, B2 x2.
    // vmcnt(8) retires the 6 oldest = A0 x4 + B0 x2 (tile 0 fully ready).
    ALOAD(0, c0, c1, c2, c3); SB0;
    BSTAGE(0, 0); SB0;
    ALOAD(1, n0, n1, n2, n3); SB0;
    BSTAGE(1, 1); BSTAGE(2, 2); SB0;
    asm volatile("s_waitcnt vmcnt(8)" ::: "memory");
    APACK(0, c0, c1, c2, c3);
    asm volatile("s_waitcnt lgkmcnt(0)" ::: "memory");
    __builtin_amdgcn_s_barrier();
    SB0;

    for (int kt = 0; kt < NT; kt += 2) {
        ITER(kt,     n0, n1, n2, n3, c0, c1, c2, c3);   // packs A(kt+1)=n, loads c
        ITER(kt + 1, c0, c1, c2, c3, n0, n1, n2, n3);   // packs A(kt+2)=c, loads n
    }

    asm volatile("s_waitcnt vmcnt(0) lgkmcnt(0)" ::: "memory");

    const int crow0 = tm + wm * 128 + quad * 4;
    const int ccol0 = tn + wn * 64 + lm;
#pragma unroll
    for (int i = 0; i < 8; ++i) {
#pragma unroll
        for (int r = 0; r < 4; ++r) {
            const int row = crow0 + i * 16 + r;
            int mz = 0;
            if constexpr (ACT == 2) mz = mask[row];
#pragma unroll
            for (int j = 0; j < 4; ++j) {
                const int col = ccol0 + j * 16;
                float v = acc[i][j][r] + bias[col];
                if constexpr (ACT >= 1) v = v > 0.f ? v : 0.f;
                if constexpr (ACT == 2) { if (mz) v = 0.f; }
                Cp[(size_t)row * DIM + col] = bf16_rne(v);
            }
        }
    }
#undef ITER
#undef APACK
#undef BSTAGE
#undef ALOAD
}

// ---- bf16-A GEMM (final projection): verified r6 structure ---------------
__global__ __launch_bounds__(512, 2) void gemm8_kernel(const unsigned short* __restrict__ Ab,
                                                       const unsigned short* __restrict__ Wb,
                                                       const float* __restrict__ bias,
                                                       float* __restrict__ Cp) {
    __shared__ __align__(16) char smem[131072];

    const int bid = blockIdx.x;
    const int swz = (bid & 7) * 32 + (bid >> 3);
    const int tm  = (swz >> 2) * 256;
    const int tn  = (swz & 3) * 256;

    const int t    = threadIdx.x;
    const int w    = t >> 6;
    const int lane = t & 63;
    const int wm   = w >> 2;
    const int wn   = w & 3;
    const int lm   = lane & 15;
    const int quad = lane >> 4;

    const int xr    = ((quad ^ ((lm >> 1) & 3)) << 4) + (lm & 1) * 64;
    const int abase = (wm * 64 + (lm >> 1)) * 128 + xr;
    const int bbase = (wn * 32 + (lm >> 1)) * 128 + xr;

    const int srow = ((t >> 3) << 1) + ((t >> 2) & 1);
    const int scol = ((t & 3) ^ ((t >> 3) & 3)) * 8;
    const unsigned short* pa = Ab + (size_t)(tm + srow) * DIM + scol;
    const unsigned short* pb = Wb + (size_t)(tn + srow) * DIM + scol;

    f32x4 acc[8][4] = {};
    const int NT = DIM / 32;

#pragma unroll
    for (int pt = 0; pt < 3; ++pt) {
        char* dst = smem + pt * 16384;
        gld16(pa + pt * 32,             (unsigned short*)(dst + t * 16));
        gld16(pa + 128 * DIM + pt * 32, (unsigned short*)(dst + 8192 + t * 16));
        gld16(pb + pt * 32,             (unsigned short*)(dst + 65536 + t * 16));
        gld16(pb + 128 * DIM + pt * 32, (unsigned short*)(dst + 65536 + 8192 + t * 16));
        __builtin_amdgcn_sched_barrier(0);
    }
    asm volatile("s_waitcnt vmcnt(8)" ::: "memory");
    __builtin_amdgcn_s_barrier();
    SB0;

    short8 bf[4];
    for (int kt = 0; kt < NT; ++kt) {
        const int  slot = (kt & 3) * 16384;
        const int  ks   = (kt + 3 < NT) ? kt + 3 : NT - 1;
        char*      stg  = smem + ((kt + 3) & 3) * 16384;

        gld16(pa + ks * 32,             (unsigned short*)(stg + t * 16));
        gld16(pa + 128 * DIM + ks * 32, (unsigned short*)(stg + 8192 + t * 16));
        short8 af[4];
#pragma unroll
        for (int i = 0; i < 4; ++i)
            af[i] = *(const short8*)(smem + slot + abase + i * 1024);
#pragma unroll
        for (int j = 0; j < 4; ++j)
            bf[j] = *(const short8*)(smem + slot + 65536 + bbase + j * 1024);
        __builtin_amdgcn_s_barrier();
        asm volatile("s_waitcnt lgkmcnt(0)" ::: "memory");
        SB0;
        __builtin_amdgcn_s_setprio(1);
#pragma unroll
        for (int i = 0; i < 4; ++i)
#pragma unroll
            for (int j = 0; j < 4; ++j)
                acc[i][j] = __builtin_amdgcn_mfma_f32_16x16x32_bf16(af[i], bf[j], acc[i][j], 0, 0, 0);
        __builtin_amdgcn_s_setprio(0);
        __builtin_amdgcn_s_barrier();
        SB0;

        gld16(pb + ks * 32,             (unsigned short*)(stg + 65536 + t * 16));
        gld16(pb + 128 * DIM + ks * 32, (unsigned short*)(stg + 65536 + 8192 + t * 16));
#pragma unroll
        for (int i = 0; i < 4; ++i)
            af[i] = *(const short8*)(smem + slot + abase + 4096 + i * 1024);
        __builtin_amdgcn_s_barrier();
        asm volatile("s_waitcnt lgkmcnt(0)" ::: "memory");
        SB0;
        __builtin_amdgcn_s_setprio(1);
#pragma unroll
        for (int i = 0; i < 4; ++i)
#pragma unroll
            for (int j = 0; j < 4; ++j)
                acc[i + 4][j] = __builtin_amdgcn_mfma_f32_16x16x32_bf16(af[i], bf[j], acc[i + 4][j], 0, 0, 0);
        __builtin_amdgcn_s_setprio(0);
        asm volatile("s_waitcnt vmcnt(8)" ::: "memory");
        __builtin_amdgcn_s_barrier();
        SB0;
    }

    asm volatile("s_waitcnt vmcnt(0)" ::: "memory");

    const int crow0 = tm + wm * 128 + quad * 4;
    const int ccol0 = tn + wn * 64 + lm;
#pragma unroll
    for (int i = 0; i < 8; ++i)
#pragma unroll
        for (int r = 0; r < 4; ++r)
#pragma unroll
            for (int j = 0; j < 4; ++j) {
                const int row = crow0 + i * 16 + r;
                const int col = ccol0 + j * 16;
                Cp[(size_t)row * DIM + col] = acc[i][j][r] + bias[col];
            }
}

// ---- kv via MFMA ---------------------------------------------------------
__device__ inline int rowoff(int d) { return d * 40 + ((d >> 3) & 1) * 8; }

__global__ __launch_bounds__(256) void kvmfma_kernel(const unsigned short* __restrict__ kb,
                                                     const unsigned short* __restrict__ vb,
                                                     float* __restrict__ kvT8,
                                                     float* __restrict__ ksum8) {
    __shared__ unsigned short kT[2624];
    __shared__ unsigned short vT[2624];
    __shared__ float ksl[64];

    const int bh    = blockIdx.x;
    const int bb    = bh >> 4, h = bh & 15;
    const int chunk = blockIdx.y;
    const int t     = threadIdx.x;
    const int w     = t >> 6;
    const int lane  = t & 63;
    const int lm    = lane & 15;
    const int quad  = lane >> 4;
    const int sn    = t >> 3;
    const int d0    = (t & 7) * 8;

    const size_t gbase = ((size_t)bb * NSEQ + (size_t)chunk * 512) * DIM + h * HD;
    const unsigned short* kp = kb + gbase + (size_t)sn * DIM + d0;
    const unsigned short* vp = vb + gbase + (size_t)sn * DIM + d0;

    if (t < 64) ksl[t] = 0.f;

    float ks[8] = {};
    f32x4 acc[4] = {};

    for (int n0 = 0; n0 < 512; n0 += 32) {
        short8 kx = *(const short8*)(kp + (size_t)n0 * DIM);
        short8 vx = *(const short8*)(vp + (size_t)n0 * DIM);
        __syncthreads();
#pragma unroll
        for (int j = 0; j < 8; ++j) {
            const int ro = rowoff(d0 + j);
            kT[ro + sn] = (unsigned short)kx[j];
            vT[ro + sn] = (unsigned short)vx[j];
            ks[j] += bf16_to_f32((unsigned short)kx[j]);
        }
        __syncthreads();
        short8 afrag = *(const short8*)(vT + rowoff(w * 16 + lm) + quad * 8);
#pragma unroll
        for (int jd = 0; jd < 4; ++jd) {
            short8 bfrag = *(const short8*)(kT + rowoff(jd * 16 + lm) + quad * 8);
            acc[jd] = __builtin_amdgcn_mfma_f32_16x16x32_bf16(afrag, bfrag, acc[jd], 0, 0, 0);
        }
    }

    const size_t obase = ((size_t)chunk * 64 + bh) * 4096;
#pragma unroll
    for (int jd = 0; jd < 4; ++jd)
#pragma unroll
        for (int r = 0; r < 4; ++r) {
            const int e = w * 16 + quad * 4 + r;
            const int d = jd * 16 + lm;
            kvT8[obase + e * 64 + d] = acc[jd][r];
        }

    __syncthreads();
#pragma unroll
    for (int j = 0; j < 8; ++j) atomicAdd(&ksl[d0 + j], ks[j]);
    __syncthreads();
    if (t < 64) ksum8[((size_t)chunk * 64 + bh) * 64 + t] = ksl[t];
}

// ---- reduce 8 chunk-slices -> kvTb bf16 + ksum fp32 ----------------------
__global__ __launch_bounds__(256) void kvsum_kernel(const float* __restrict__ kvT8,
                                                    const float* __restrict__ ksum8,
                                                    unsigned short* __restrict__ kvTb,
                                                    float* __restrict__ ksum) {
    int idx = blockIdx.x * 256 + threadIdx.x;
    if (idx < 262144) {
        float s = 0.f;
#pragma unroll
        for (int c = 0; c < 8; ++c) s += kvT8[(size_t)c * 262144 + idx];
        kvTb[idx] = bf16_rne(s);
    } else {
        int j = idx - 262144;
        float s = 0.f;
#pragma unroll
        for (int c = 0; c < 8; ++c) s += ksum8[(size_t)c * 4096 + j];
        ksum[j] = s;
    }
}

// ---- attention apply + fused denominator ---------------------------------
__global__ __launch_bounds__(256) void attnout_kernel(const unsigned short* __restrict__ qb,
                                                      const unsigned short* __restrict__ kvTb,
                                                      const float* __restrict__ ksum,
                                                      unsigned short* __restrict__ attn) {
    const int n0   = blockIdx.x * 16;
    const int bb   = n0 >> 12;
    const int t    = threadIdx.x;
    const int w    = t >> 6;
    const int lane = t & 63;
    const int lm   = lane & 15;
    const int quad = lane >> 4;

    for (int hh = 0; hh < 4; ++hh) {
        const int h  = w * 4 + hh;
        const int bh = bb * NH + h;
        const unsigned short* qp = qb + (size_t)(n0 + lm) * DIM + h * HD + quad * 8;
        short8 a0 = *(const short8*)qp;
        short8 a1 = *(const short8*)(qp + 32);

        const float* ksp = ksum + (size_t)bh * HD + quad * 8;
        float part = 0.f;
#pragma unroll
        for (int j = 0; j < 8; ++j)
            part += bf16_to_f32((unsigned short)a0[j]) * ksp[j]
                  + bf16_to_f32((unsigned short)a1[j]) * ksp[32 + j];
        part += __shfl_xor(part, 16, 64);
        part += __shfl_xor(part, 32, 64);
        float dinv = 1.f / (part + 1e-6f);

        f32x4 accs[4];
#pragma unroll
        for (int j = 0; j < 4; ++j) {
            const unsigned short* bp = kvTb + ((size_t)bh * HD + j * 16 + lm) * HD + quad * 8;
            short8 b0 = *(const short8*)bp;
            short8 b1 = *(const short8*)(bp + 32);
            f32x4 c = {};
            c = __builtin_amdgcn_mfma_f32_16x16x32_bf16(a0, b0, c, 0, 0, 0);
            c = __builtin_amdgcn_mfma_f32_16x16x32_bf16(a1, b1, c, 0, 0, 0);
            accs[j] = c;
        }
        float dv[4];
#pragma unroll
        for (int r = 0; r < 4; ++r)
            dv[r] = __shfl(dinv, quad * 4 + r, 64);
#pragma unroll
        for (int j = 0; j < 4; ++j)
#pragma unroll
            for (int r = 0; r < 4; ++r) {
                const int row = n0 + quad * 4 + r;
                attn[(size_t)row * DIM + h * HD + j * 16 + lm] = bf16_rne(accs[j][r] * dv[r]);
            }
    }
}

// ---- host ----------------------------------------------------------------
extern "C" void kernel_launch(void* const* d_in, const int* in_sizes, int n_in,
                              void* d_out, int out_size, void* d_ws, size_t ws_size,
                              hipStream_t stream) {
    const float* query = (const float*)d_in[0];
    const float* key   = (const float*)d_in[1];
    const float* value = (const float*)d_in[2];
    const float* Wq    = (const float*)d_in[3];
    const float* bq    = (const float*)d_in[4];
    const float* Wk    = (const float*)d_in[5];
    const float* bk    = (const float*)d_in[6];
    const float* Wv    = (const float*)d_in[7];
    const float* bv    = (const float*)d_in[8];
    const float* Wo    = (const float*)d_in[9];
    const float* bo    = (const float*)d_in[10];
    const int*   mask  = (const int*)d_in[11];
    float* out = (float*)d_out;
    char*  ws  = (char*)d_ws;
    const size_t MB = 1024ull * 1024ull;

    // ws layout (74 MB):
    unsigned short* Wqb  = (unsigned short*)(ws + 0 * MB);
    unsigned short* Wkb  = (unsigned short*)(ws + 2 * MB);
    unsigned short* Wvb  = (unsigned short*)(ws + 4 * MB);
    unsigned short* Wob  = (unsigned short*)(ws + 6 * MB);
    unsigned short* qb   = (unsigned short*)(ws + 8 * MB);    // 32 MB
    unsigned short* kb   = (unsigned short*)(ws + 40 * MB);   // 32 MB (reused as attn)
    unsigned short* kvTb = (unsigned short*)(ws + 72 * MB);   // 0.5 MB
    float*          ksum = (float*)(ws + 73 * MB);            // 16 KB
    unsigned short* attn = kb;

    // d_out (64 MB) scratch: vb [0:32) live gemmV->kvmfma;
    // kvT8/ksum8 [32:40.125) live kvmfma->kvsum; out written by final GEMM.
    unsigned short* vb    = (unsigned short*)d_out;
    float*          kvT8  = (float*)((char*)d_out + 32 * MB);
    float*          ksum8 = (float*)((char*)d_out + 40 * MB);

    wcvt_kernel<<<2048, 256, 0, stream>>>(Wq, Wk, Wv, Wo, Wqb, Wkb, Wvb, Wob);

    gemm8a32_kernel<1><<<256, 512, 0, stream>>>(query, Wqb, bq, qb, nullptr);
    gemm8a32_kernel<2><<<256, 512, 0, stream>>>(key,   Wkb, bk, kb, mask);
    gemm8a32_kernel<0><<<256, 512, 0, stream>>>(value, Wvb, bv, vb, nullptr);

    kvmfma_kernel<<<dim3(64, 8), 256, 0, stream>>>(kb, vb, kvT8, ksum8);
    kvsum_kernel<<<1040, 256, 0, stream>>>(kvT8, ksum8, kvTb, ksum);
    attnout_kernel<<<1024, 256, 0, stream>>>(qb, kvTb, ksum, attn);

    gemm8_kernel<<<256, 512, 0, stream>>>(attn, Wob, bo, out);
}